// Round 12
// baseline (27.966 us; speedup 1.0000x reference)
//
#include <hip/hip_runtime.h>
#include <hip/hip_bf16.h>
#include <float.h>

// MeshLoss: out = mean_b,m( min_n |pc[b,m]-top[b,n]|^2 ) + mean((bottom-fem_bottom)^2)
// network_mesh (4,3,32,16,32) f32, pc (4,3,16384) f32, fem_mesh (4,3,32,16,32) f32.
// top[b,n] = network_mesh[b,:, n>>5, 15, n&31], n in [0,1024)
//
// |p-t|^2 = |p|^2 + (|t|^2 - 2 p.t): d' = 3 FMA/pair, folded pairwise into
// v_min3_f32.
//
// R11 post-mortem: K1-internal changes (LDS traffic, waves/SIMD, tail) all
// flat at 14.1-14.6 -> ~8-9us is two-dispatch replay machinery. R12: SINGLE
// kernel node. R10 showed 256 same-address atomics cost 6-10us, so the
// single-kernel ending uses a last-block-done gate with a 2-LEVEL COUNTER
// TREE (16 leaf counters on separate cachelines + 1 master): max 16
// serialized RMWs per address (~0.6us total). Winner block sums the 256
// partials in FIXED index order (deterministic) -> out[0]. Counters zeroed
// per launch by a 4KB memset node. No dispatch-order assumptions.
//
// K1 body = R11's proven kernel: 256 blocks x 1024 thr (1 block/CU),
// block = (batch, 256-pt chunk); SoA tops; 16 waves partition the 1024 tops
// (64 each); per-wave mins (+|p|^2) -> pm[16][256] -> 16-way min (t<256)
// overlapped with fem slice (t in [256,436)); block partial -> ws[bid].

#define NM_BATCH_STRIDE 49152     // 3*32*16*32 (== pc batch stride)
#define CH_STRIDE       16384
#define NTOP            1024
#define NWAVES          16
#define TOPS_PER_WAVE   64        // 1024 / 16 waves
#define NBLK            256
#define NTHR            1024
#define FEM_PER_BLK     180       // 46080 float4 pairs / 256 blocks

// ws layout: float ws[0..255] block partials; int counters at byte 4096:
//   leaf i (i<16) at int index 1024 + 32*i (128B apart); master at 1024+512.
#define CNT_BASE_INT    1024
#define CNT_STRIDE      32
#define MASTER_OFF      512

__global__ __launch_bounds__(NTHR) void meshloss_fused(
    const float* __restrict__ nm,
    const float* __restrict__ pc,
    const float* __restrict__ fem,
    float* __restrict__ ws,
    float* __restrict__ out)
{
    __shared__ __align__(16) float xs[NTOP];   // 4 KB each
    __shared__ __align__(16) float ys[NTOP];
    __shared__ __align__(16) float zs[NTOP];
    __shared__ float pm[NWAVES * 256];         // 16 KB per-wave partial mins
    __shared__ float wsum[NWAVES];
    __shared__ int   isLast;

    const int t     = threadIdx.x;
    const int b     = blockIdx.x >> 6;      // batch
    const int chunk = blockIdx.x & 63;      // 256-point chunk
    const int w     = t >> 6;               // wave 0..15
    const int l     = t & 63;               // lane

    // ---- stage tops (j==15 slice) as SoA: one top per thread ----
    const float* nmb = nm + b * NM_BATCH_STRIDE;
    {
        const int i = t >> 5, k = t & 31;
        const int base = i * 512 + 480 + k;          // (i*16+15)*32 + k
        xs[t] = nmb[0 * CH_STRIDE + base];
        ys[t] = nmb[1 * CH_STRIDE + base];
        zs[t] = nmb[2 * CH_STRIDE + base];
    }

    // ---- this lane's 4 points (same 4 points in every wave) ----
    const float* pcb = pc + b * NM_BATCH_STRIDE;
    const int m0 = chunk * 256 + l;                  // point p_j = l + j*64
    float px2[4], py2[4], pz2[4], pp[4], mn[4];
    #pragma unroll
    for (int j = 0; j < 4; ++j) {
        const int m = m0 + j * 64;
        float x = pcb[m];
        float y = pcb[CH_STRIDE + m];
        float z = pcb[2 * CH_STRIDE + m];
        pp[j]  = x * x + y * y + z * z;
        px2[j] = -2.0f * x;
        py2[j] = -2.0f * y;
        pz2[j] = -2.0f * z;
        mn[j]  = FLT_MAX;
    }
    __syncthreads();

    // ---- wave w scans its 64-top share for all 4 points/lane ----
    const float4* xs4 = reinterpret_cast<const float4*>(xs);
    const float4* ys4 = reinterpret_cast<const float4*>(ys);
    const float4* zs4 = reinterpret_cast<const float4*>(zs);
    const int base4 = w * (TOPS_PER_WAVE / 4);       // float4 index of share

    #pragma unroll 2
    for (int g = 0; g < TOPS_PER_WAVE / 8; ++g) {
        float4 X0 = xs4[base4 + 2 * g];
        float4 X1 = xs4[base4 + 2 * g + 1];
        float4 Y0 = ys4[base4 + 2 * g];
        float4 Y1 = ys4[base4 + 2 * g + 1];
        float4 Z0 = zs4[base4 + 2 * g];
        float4 Z1 = zs4[base4 + 2 * g + 1];
        float tx[8] = {X0.x, X0.y, X0.z, X0.w, X1.x, X1.y, X1.z, X1.w};
        float ty[8] = {Y0.x, Y0.y, Y0.z, Y0.w, Y1.x, Y1.y, Y1.z, Y1.w};
        float tz[8] = {Z0.x, Z0.y, Z0.z, Z0.w, Z1.x, Z1.y, Z1.z, Z1.w};
        float t2[8];
        #pragma unroll
        for (int e = 0; e < 8; ++e)
            t2[e] = __builtin_fmaf(tx[e], tx[e],
                    __builtin_fmaf(ty[e], ty[e], tz[e] * tz[e]));
        #pragma unroll
        for (int j = 0; j < 4; ++j) {
            #define DISTD(e) __builtin_fmaf(px2[j], tx[e], \
                             __builtin_fmaf(py2[j], ty[e], \
                             __builtin_fmaf(pz2[j], tz[e], t2[e])))
            float d0 = DISTD(0);
            float d1 = DISTD(1);
            float d2 = DISTD(2);
            float d3 = DISTD(3);
            float d4 = DISTD(4);
            float d5 = DISTD(5);
            float d6 = DISTD(6);
            float d7 = DISTD(7);
            #undef DISTD
            mn[j] = fminf(mn[j], fminf(d0, d1));   // v_min3_f32
            mn[j] = fminf(mn[j], fminf(d2, d3));
            mn[j] = fminf(mn[j], fminf(d4, d5));
            mn[j] = fminf(mn[j], fminf(d6, d7));
        }
    }

    // ---- per-wave partial (+|p|^2, commutes with cross-wave min) ----
    #pragma unroll
    for (int j = 0; j < 4; ++j)
        pm[w * 256 + l + j * 64] = mn[j] + pp[j];
    __syncthreads();

    // ---- tail, parallel across waves: min combine (t<256) | fem (256..435) ----
    float v = 0.0f;
    if (t < 256) {
        float d = pm[t];
        #pragma unroll
        for (int ww = 1; ww < NWAVES; ++ww)
            d = fminf(d, pm[ww * 256 + t]);
        v = d * (1.0f / 65536.0f);
    } else if (t < 256 + FEM_PER_BLK) {
        const int q   = blockIdx.x * FEM_PER_BLK + (t - 256);   // < 46080
        const int bci = q / 120;
        const int r   = q - bci * 120;
        const int s   = bci * 128 + r;
        float4 a = reinterpret_cast<const float4*>(nm)[s];
        float4 f = reinterpret_cast<const float4*>(fem)[s];
        float dx = a.x - f.x, dy = a.y - f.y, dz = a.z - f.z, dw = a.w - f.w;
        v = (dx * dx + dy * dy + dz * dz + dw * dw) * (1.0f / 184320.0f);
    }

    // ---- block reduce (16 waves) ----
    for (int o = 32; o > 0; o >>= 1) v += __shfl_down(v, o, 64);
    if (l == 0) wsum[w] = v;
    __syncthreads();

    // ---- publish partial + 2-level last-block gate ----
    int* cnt = reinterpret_cast<int*>(ws) + CNT_BASE_INT;
    if (t == 0) {
        float s = 0.0f;
        #pragma unroll
        for (int ww = 0; ww < NWAVES; ++ww) s += wsum[ww];
        ws[blockIdx.x] = s;
        __threadfence();                               // release partial
        isLast = 0;
        int old = __hip_atomic_fetch_add(&cnt[(blockIdx.x & 15) * CNT_STRIDE],
                                         1, __ATOMIC_ACQ_REL,
                                         __HIP_MEMORY_SCOPE_AGENT);
        if (old == 15) {                               // last of this leaf's 16
            int old2 = __hip_atomic_fetch_add(&cnt[MASTER_OFF], 1,
                                              __ATOMIC_ACQ_REL,
                                              __HIP_MEMORY_SCOPE_AGENT);
            if (old2 == 15) isLast = 1;                // last leaf overall
        }
    }
    __syncthreads();

    // ---- winner block: fixed-order deterministic sum of 256 partials ----
    if (isLast && t < 64) {
        __threadfence();                               // acquire
        float acc = 0.0f;
        #pragma unroll
        for (int h = 0; h < 4; ++h)                    // fixed order: t, t+64, ...
            acc += __hip_atomic_load(&ws[t + h * 64], __ATOMIC_ACQUIRE,
                                     __HIP_MEMORY_SCOPE_AGENT);
        for (int o = 32; o > 0; o >>= 1) acc += __shfl_down(acc, o, 64);
        if (t == 0) out[0] = acc;
    }
}

extern "C" void kernel_launch(void* const* d_in, const int* in_sizes, int n_in,
                              void* d_out, int out_size, void* d_ws, size_t ws_size,
                              hipStream_t stream) {
    const float* nm  = (const float*)d_in[0];
    const float* pc  = (const float*)d_in[1];
    const float* fem = (const float*)d_in[2];
    float* out = (float*)d_out;
    float* ws  = (float*)d_ws;

    // zero the counter region (bytes 4096..8192 of ws) each launch
    hipMemsetAsync((char*)d_ws + 4096, 0, 4096, stream);
    meshloss_fused<<<NBLK, NTHR, 0, stream>>>(nm, pc, fem, ws, out);
}

// Round 13
// 14.078 us; speedup vs baseline: 1.9866x; 1.9866x over previous
//
#include <hip/hip_runtime.h>
#include <hip/hip_bf16.h>
#include <float.h>

// MeshLoss: out = mean_b,m( min_n |pc[b,m]-top[b,n]|^2 ) + mean((bottom-fem_bottom)^2)
// network_mesh (4,3,32,16,32) f32, pc (4,3,16384) f32, fem_mesh (4,3,32,16,32) f32.
// top[b,n] = network_mesh[b,:, n>>5, 15, n&31], n in [0,1024)
//
// |p-t|^2 = |p|^2 + (|t|^2 - 2 p.t): tops staged as (x,y,z,|t|^2); per pair
// d' = fma(-2px,tx, fma(-2py,ty, fma(-2pz,tz, t2))) = 3 FMA, folded pairwise
// into v_min3_f32 -> 3.5 VALU/pair.
//
// CHAMPION (R7, 14.06us) restored verbatim. Session synthesis:
//  - fusion attempts all lose: cooperative grid-sync (+60us), 256 same-address
//    atomics (+6us), last-block gate w/ cross-XCD acquire loads (+14us);
//  - K1-internal variants spanning 2x modeled pipe cost are FLAT (14.1-14.6)
//    -> at this operating point total = ~5-6us kernel + ~8-9us fixed
//    two-dispatch replay machinery; kernel-side levers are invisible.
//
// K1: 256 blocks x 512 thr (1 block/CU). Block = (batch, 256-pt chunk).
//     All 1024 tops staged once in LDS (16 KB); 8 waves PARTITION the tops
//     (128 each); each wave covers all 256 block points (4/lane) -> each top
//     LDS-read exactly once per block. Per-wave mins (+|p|^2) -> pm[8][256]
//     -> 8-way min by t<256; fem slice (180 float4 pairs) folded in; block
//     partial -> ws[block] (plain store).
// K2: 1 block x 256 thr: fixed-order sum of the 256 partials -> out[0].
//     No atomics anywhere; bit-deterministic.

#define B_BATCH         4
#define NM_BATCH_STRIDE 49152     // 3*32*16*32 (== pc batch stride)
#define CH_STRIDE       16384
#define NTOP            1024
#define TOPS_PER_WAVE   128       // 1024 / 8 waves
#define NBLK            256
#define NTHR            512
#define FEM_PER_BLK     180       // 46080 float4 pairs / 256 blocks

__global__ __launch_bounds__(NTHR) void meshloss_fused(
    const float* __restrict__ nm,
    const float* __restrict__ pc,
    const float* __restrict__ fem,
    float* __restrict__ ws)
{
    __shared__ float4 top[NTOP];        // 16 KB
    __shared__ float  pm[8 * 256];      // 8 KB: per-wave partial mins
    __shared__ float  wsum[8];

    const int t     = threadIdx.x;
    const int b     = blockIdx.x >> 6;      // batch
    const int chunk = blockIdx.x & 63;      // 256-point chunk
    const int w     = t >> 6;               // wave 0..7
    const int l     = t & 63;               // lane

    // ---- stage all 1024 tops (j==15 slice) with |t|^2 ----
    const float* nmb = nm + b * NM_BATCH_STRIDE;
    #pragma unroll
    for (int p0 = 0; p0 < NTOP; p0 += NTHR) {
        const int p = p0 + t;
        const int i = p >> 5, k = p & 31;
        const int base = i * 512 + 480 + k;          // (i*16+15)*32 + k
        float x = nmb[0 * CH_STRIDE + base];
        float y = nmb[1 * CH_STRIDE + base];
        float z = nmb[2 * CH_STRIDE + base];
        top[p] = make_float4(x, y, z, x * x + y * y + z * z);
    }

    // ---- load this lane's 4 points (same 4 points in every wave) ----
    const float* pcb = pc + b * NM_BATCH_STRIDE;
    const int m0 = chunk * 256 + l;                  // point p_j = l + j*64
    float px2[4], py2[4], pz2[4], pp[4], mn[4];
    #pragma unroll
    for (int j = 0; j < 4; ++j) {
        const int m = m0 + j * 64;
        float x = pcb[m];
        float y = pcb[CH_STRIDE + m];
        float z = pcb[2 * CH_STRIDE + m];
        pp[j]  = x * x + y * y + z * z;
        px2[j] = -2.0f * x;
        py2[j] = -2.0f * y;
        pz2[j] = -2.0f * z;
        mn[j]  = FLT_MAX;
    }
    __syncthreads();

    // ---- wave w scans its 128-top share for all 4 points/lane ----
    const float4* wtop = top + w * TOPS_PER_WAVE;
    #pragma unroll 2
    for (int g = 0; g < TOPS_PER_WAVE / 8; ++g) {
        float4 T0 = wtop[g * 8 + 0];
        float4 T1 = wtop[g * 8 + 1];
        float4 T2 = wtop[g * 8 + 2];
        float4 T3 = wtop[g * 8 + 3];
        float4 T4 = wtop[g * 8 + 4];
        float4 T5 = wtop[g * 8 + 5];
        float4 T6 = wtop[g * 8 + 6];
        float4 T7 = wtop[g * 8 + 7];
        #pragma unroll
        for (int j = 0; j < 4; ++j) {
            #define DISTD(T) __builtin_fmaf(px2[j], T.x, \
                             __builtin_fmaf(py2[j], T.y, \
                             __builtin_fmaf(pz2[j], T.z, T.w)))
            float d0 = DISTD(T0);
            float d1 = DISTD(T1);
            float d2 = DISTD(T2);
            float d3 = DISTD(T3);
            float d4 = DISTD(T4);
            float d5 = DISTD(T5);
            float d6 = DISTD(T6);
            float d7 = DISTD(T7);
            #undef DISTD
            mn[j] = fminf(mn[j], fminf(d0, d1));   // v_min3_f32
            mn[j] = fminf(mn[j], fminf(d2, d3));
            mn[j] = fminf(mn[j], fminf(d4, d5));
            mn[j] = fminf(mn[j], fminf(d6, d7));
        }
    }

    // ---- per-wave partial (+|p|^2, commutes with cross-wave min) ----
    #pragma unroll
    for (int j = 0; j < 4; ++j)
        pm[w * 256 + l + j * 64] = mn[j] + pp[j];
    __syncthreads();

    // ---- 8-way min combine (threads 0..255) ----
    float v = 0.0f;
    if (t < 256) {
        float d = pm[t];
        #pragma unroll
        for (int ww = 1; ww < 8; ++ww)
            d = fminf(d, pm[ww * 256 + t]);
        v = d * (1.0f / 65536.0f);
    }

    // ---- fem MSE slice: 180 float4 pairs per block ----
    if (t < FEM_PER_BLK) {
        const int q   = blockIdx.x * FEM_PER_BLK + t;   // < 46080
        const int bci = q / 120;
        const int r   = q - bci * 120;
        const int s   = bci * 128 + r;
        float4 a = reinterpret_cast<const float4*>(nm)[s];
        float4 f = reinterpret_cast<const float4*>(fem)[s];
        float dx = a.x - f.x, dy = a.y - f.y, dz = a.z - f.z, dw = a.w - f.w;
        v += (dx * dx + dy * dy + dz * dz + dw * dw) * (1.0f / 184320.0f);
    }

    // ---- block reduce (8 waves) + plain store of block partial ----
    for (int o = 32; o > 0; o >>= 1) v += __shfl_down(v, o, 64);
    if (l == 0) wsum[w] = v;
    __syncthreads();
    if (t == 0) {
        float s = 0.0f;
        #pragma unroll
        for (int ww = 0; ww < 8; ++ww) s += wsum[ww];
        ws[blockIdx.x] = s;
    }
}

__global__ __launch_bounds__(256) void meshloss_final(
    const float* __restrict__ ws, float* __restrict__ out)
{
    __shared__ float s4[4];
    const int t = threadIdx.x;
    float v = ws[t];
    for (int o = 32; o > 0; o >>= 1) v += __shfl_down(v, o, 64);
    if ((t & 63) == 0) s4[t >> 6] = v;
    __syncthreads();
    if (t == 0) out[0] = s4[0] + s4[1] + s4[2] + s4[3];
}

extern "C" void kernel_launch(void* const* d_in, const int* in_sizes, int n_in,
                              void* d_out, int out_size, void* d_ws, size_t ws_size,
                              hipStream_t stream) {
    const float* nm  = (const float*)d_in[0];
    const float* pc  = (const float*)d_in[1];
    const float* fem = (const float*)d_in[2];
    float* out = (float*)d_out;
    float* ws  = (float*)d_ws;

    meshloss_fused<<<NBLK, NTHR, 0, stream>>>(nm, pc, fem, ws);
    meshloss_final<<<1, 256, 0, stream>>>(ws, out);
}